// Round 10
// baseline (701.976 us; speedup 1.0000x reference)
//
#include <hip/hip_runtime.h>
#include <hip/hip_bf16.h>
#include <cmath>

// Problem constants
#define BB 64
#define TT 2048
#define EE 1024
#define DD 1024
#define FAN 2048

typedef __attribute__((ext_vector_type(8))) short bhalf8;
typedef __attribute__((ext_vector_type(4))) float fvec4;

// ws layout (bytes)
#define OFF_WE   0u          // 2 MB  : We bf16 image [ec32][dq4][eo4][dloc256][8e]
#define OFF_C    2097152u    // 256 KB: c[b,d] = dec·Wd + bias
#define OFF_SP   2359296u    // 2 MB  : score partials [4 dq][64 b][2048 t]
#define OFF_A    4456448u    // 512 KB: alpha[b,t]
#define OFF_P    4980736u    // 2 MB  : context partials [8 ts][64 b][1024 e]

__device__ __forceinline__ short f2bf(float f) {
    unsigned int u = __float_as_uint(f);
    u += 0x7FFFu + ((u >> 16) & 1u);   // round-to-nearest-even
    return (short)(u >> 16);
}

__device__ __forceinline__ bhalf8 cvt8(float4 a, float4 b) {
    bhalf8 h;
    h[0] = f2bf(a.x); h[1] = f2bf(a.y); h[2] = f2bf(a.z); h[3] = f2bf(a.w);
    h[4] = f2bf(b.x); h[5] = f2bf(b.y); h[6] = f2bf(b.z); h[7] = f2bf(b.w);
    return h;
}

__device__ __forceinline__ float fast_tanhf(float x) {
    float ax = __builtin_fabsf(x);
    float e  = __expf(-2.0f * ax);
    float r  = (1.0f - e) * __builtin_amdgcn_rcpf(1.0f + e);
    return __builtin_copysignf(r, x);
}

__device__ __forceinline__ void dma16(const void* g, void* l) {
    __builtin_amdgcn_global_load_lds(
        (const __attribute__((address_space(1))) void*)g,
        (__attribute__((address_space(3))) void*)l,
        16, 0, 0);
}

// ---------------- kernel 0a: We (f32) -> bf16 image -------------------------
// layout: byte = ec*65536 + dq*16384 + eo*4096 + dloc*16  (per-(ec,dq) slab
// is a contiguous 16 KB => scores_k B-DMA is a pure linear copy)
__global__ void prep_we_k(const float* __restrict__ W, short* __restrict__ wsWe) {
    int g  = blockIdx.x * 256 + threadIdx.x;   // 0..131071
    int ec = g >> 12;          // 0..31
    int eo = (g >> 10) & 3;    // 0..3
    int d  = g & 1023;
    int dq = d >> 8, dloc = d & 255;
    const float* src = W + (size_t)d * FAN + ec * 32 + eo * 8;
    float4 f0 = *(const float4*)src;
    float4 f1 = *(const float4*)(src + 4);
    *(bhalf8*)((char*)wsWe + (size_t)ec * 65536 + dq * 16384 + eo * 4096 + dloc * 16)
        = cvt8(f0, f1);
}

// ---------------- kernel 0b: c[b,d] = dec[b,:]·Wd[d,:] + bias[d] ------------
__global__ void prep_c_k(const float* __restrict__ W, const float* __restrict__ bias,
                         const float* __restrict__ dec, float* __restrict__ cbuf) {
    int wg   = blockIdx.x * 4 + (threadIdx.x >> 6);  // 0..65535
    int lane = threadIdx.x & 63;
    int b = wg >> 10, d = wg & 1023;
    const float* wrow = W + (size_t)d * FAN + EE;    // Wd part
    const float* drow = dec + b * DD;
    float p = 0.f;
#pragma unroll
    for (int i = 0; i < 16; ++i)
        p += wrow[i * 64 + lane] * drow[i * 64 + lane];
#pragma unroll
    for (int off = 1; off < 64; off <<= 1)
        p += __shfl_xor(p, off);
    if (lane == 0) cbuf[b * DD + d] = p + bias[d];
}

// ---------------- kernel 1: partial scores, m201-style counted pipeline -----
// BM=256t x BN=256d x BK=32e. 8 waves 2m x 4n, wave-tile 128x64, acc=128.
// Triple-buffered A (fp32, 3x32KB) and B (bf16 image slab, 3x16KB), all via
// global_load_lds. Depth-2: iter i stages tile i+2; end-of-iter wait is
// vmcnt(6) (one tile in flight) — NEVER 0 until the 2-iter tail (T4).
// A: linear LDS dest + inverse-XOR global src + XOR read (rule #21).
__global__ __launch_bounds__(512, 2)
void scores_k(const float* __restrict__ enc, const short* __restrict__ wsWe,
              const float* __restrict__ cbuf, const float* __restrict__ vw,
              float* __restrict__ sp) {
    __shared__ __align__(16) char smA[3][32768];   // 96 KB fp32 A [256t][128B]
    __shared__ __align__(16) char smB[3][16384];   // 48 KB bf16 B slab
    __shared__ float sRed[8][128];                 // 4 KB

    const int tid  = threadIdx.x;
    const int w    = tid >> 6;
    const int wm   = w >> 2;      // 0..1 (t half)
    const int wn   = w & 3;       // 0..3 (d slice)
    const int lane = tid & 63;
    const int lrow = lane >> 4;   // 0..3 (e-octet)
    const int lcol = lane & 15;
    const int b  = blockIdx.y;
    const int tt = blockIdx.x >> 2;     // 0..7
    const int dq = blockIdx.x & 3;      // 0..3 (low bits: same-A blocks co-run)
    const int t0 = tt * 256;

    // A-DMA: lds linear dest tid*16 + j*8192 -> (t = (tid>>3)+j*64, x=(tid&7)*16)
    // global src pre-applies the XOR swizzle (same involution as the read)
    const int arow = tid >> 3;
    const int xsw  = ((tid & 7) * 16) ^ ((arow & 7) << 4);
    const char* gA = (const char*)enc + ((size_t)(b * TT + t0 + arow)) * 4096 + xsw;
    // B-DMA: linear copy of 16 KB slab (ec, dq)
    const char* gB = (const char*)wsWe + (size_t)dq * 16384 + tid * 16;

    fvec4 acc[8][4];
#pragma unroll
    for (int m = 0; m < 8; ++m)
#pragma unroll
        for (int n = 0; n < 4; ++n)
            acc[m][n] = (fvec4){0.f, 0.f, 0.f, 0.f};

    // stage tile k into slot s (6 DMA ops: 2 B + 4 A)
#define STAGE(k, s)                                                          \
    do {                                                                     \
        _Pragma("unroll")                                                    \
        for (int j = 0; j < 2; ++j)                                          \
            dma16(gB + (size_t)(k) * 65536 + j * 8192,                       \
                  &smB[(s)][tid * 16 + j * 8192]);                           \
        _Pragma("unroll")                                                    \
        for (int j = 0; j < 4; ++j)                                          \
            dma16(gA + (size_t)j * 262144 + (size_t)(k) * 128,               \
                  &smA[(s)][tid * 16 + j * 8192]);                           \
    } while (0)

    // per-lane read offsets
    const int sw0 = (lrow * 32)      ^ ((lcol & 7) << 4);
    const int sw1 = (lrow * 32 + 16) ^ ((lcol & 7) << 4);
    const int bfb = lrow * 4096 + (wn * 64 + lcol) * 16;

#define BODY(i, s, DO_STAGE, ss, WAITN)                                      \
    do {                                                                     \
        if (DO_STAGE) STAGE((i) + 2, ss);                                    \
        const char* Ab = smA[(s)];                                           \
        const char* Bb = smB[(s)];                                           \
        bhalf8 bf[4];                                                        \
        _Pragma("unroll")                                                    \
        for (int n = 0; n < 4; ++n)                                          \
            bf[n] = *(const bhalf8*)(Bb + bfb + n * 256);                    \
        bhalf8 af[8];                                                        \
        _Pragma("unroll")                                                    \
        for (int m = 0; m < 8; ++m) {                                        \
            int t = wm * 128 + m * 16 + lcol;                                \
            float4 f0 = *(const float4*)(Ab + t * 128 + sw0);                \
            float4 f1 = *(const float4*)(Ab + t * 128 + sw1);                \
            af[m] = cvt8(f0, f1);                                            \
        }                                                                    \
        __builtin_amdgcn_s_setprio(1);                                       \
        _Pragma("unroll")                                                    \
        for (int n = 0; n < 4; ++n)                                          \
            _Pragma("unroll")                                                \
            for (int m = 0; m < 8; ++m)                                      \
                acc[m][n] = __builtin_amdgcn_mfma_f32_16x16x32_bf16(         \
                    af[m], bf[n], acc[m][n], 0, 0, 0);                       \
        __builtin_amdgcn_s_setprio(0);                                       \
        asm volatile("s_waitcnt vmcnt(" #WAITN ")" ::: "memory");            \
        __builtin_amdgcn_s_barrier();                                        \
    } while (0)

    // prologue: tiles 0,1 staged; wait tile-0's 6 ops (vmcnt(6)); barrier
    STAGE(0, 0);
    STAGE(1, 1);
    asm volatile("s_waitcnt vmcnt(6)" ::: "memory");
    __builtin_amdgcn_s_barrier();

    // main: 10 triples, slots compile-time (i%3 = 0,1,2)
    for (int ii = 0; ii < 30; ii += 3) {
        BODY(ii + 0, 0, 1, 2, 6);
        BODY(ii + 1, 1, 1, 0, 6);
        BODY(ii + 2, 2, 1, 1, 6);
    }
    // tail: iters 30 (slot 0), 31 (slot 1), no staging, drain
    BODY(30, 0, 0, 0, 0);
    BODY(31, 1, 0, 0, 0);
#undef BODY
#undef STAGE

    float cv[4], vv[4];
#pragma unroll
    for (int n = 0; n < 4; ++n) {
        int d = dq * 256 + wn * 64 + n * 16 + lcol;
        cv[n] = cbuf[b * DD + d];
        vv[n] = vw[d];
    }

    // epilogue: tanh + partial v-dot (this wave's 64 d), reduce over lcol
#pragma unroll
    for (int m = 0; m < 8; ++m) {
#pragma unroll
        for (int j = 0; j < 4; ++j) {
            float p = 0.f;
#pragma unroll
            for (int n = 0; n < 4; ++n)
                p += vv[n] * fast_tanhf(acc[m][n][j] + cv[n]);
            p += __shfl_xor(p, 1); p += __shfl_xor(p, 2);
            p += __shfl_xor(p, 4); p += __shfl_xor(p, 8);
            if (lcol == 0) sRed[w][m * 16 + lrow * 4 + j] = p;
        }
    }
    __syncthreads();
    if (tid < 256) {
        int r  = tid;
        int rm = r >> 7, lr = r & 127;
        float v2 = sRed[rm * 4 + 0][lr] + sRed[rm * 4 + 1][lr]
                 + sRed[rm * 4 + 2][lr] + sRed[rm * 4 + 3][lr];
        sp[((size_t)dq * BB + b) * TT + t0 + r] = v2;
    }
}

// ---------------- kernel 2: sum partials + softmax over t per batch ---------
__global__ void softmax_k(const float* __restrict__ sp, float* __restrict__ alpha) {
    int b = blockIdx.x, tid = threadIdx.x;
    float s[8];
    float m = -1e30f;
#pragma unroll
    for (int i = 0; i < 8; ++i) {
        size_t idx = (size_t)b * TT + i * 256 + tid;
        s[i] = sp[idx] + sp[(size_t)BB * TT + idx]
             + sp[2 * (size_t)BB * TT + idx] + sp[3 * (size_t)BB * TT + idx];
        m = fmaxf(m, s[i]);
    }
#pragma unroll
    for (int off = 1; off < 64; off <<= 1) m = fmaxf(m, __shfl_xor(m, off));
    __shared__ float red[4], red2[4];
    if ((tid & 63) == 0) red[tid >> 6] = m;
    __syncthreads();
    m = fmaxf(fmaxf(red[0], red[1]), fmaxf(red[2], red[3]));
    float sum = 0.f;
#pragma unroll
    for (int i = 0; i < 8; ++i) { s[i] = expf(s[i] - m); sum += s[i]; }
#pragma unroll
    for (int off = 1; off < 64; off <<= 1) sum += __shfl_xor(sum, off);
    if ((tid & 63) == 0) red2[tid >> 6] = sum;
    __syncthreads();
    sum = red2[0] + red2[1] + red2[2] + red2[3];
    float inv = 1.0f / sum;
#pragma unroll
    for (int i = 0; i < 8; ++i) alpha[b * TT + i * 256 + tid] = s[i] * inv;
}

// ---------------- kernel 3: context partials over t-slices ------------------
__global__ void ctx_k(const float* __restrict__ enc, const float* __restrict__ alpha,
                      float* __restrict__ part) {
    int ts = blockIdx.x, b = blockIdx.y, tid = threadIdx.x;
    __shared__ float sAl[256];
    sAl[tid] = alpha[b * TT + ts * 256 + tid];
    __syncthreads();
    float4 acc = {0.f, 0.f, 0.f, 0.f};
    const float* base = enc + ((size_t)b * TT + ts * 256) * EE + tid * 4;
#pragma unroll 8
    for (int i = 0; i < 256; ++i) {
        float4 v = *(const float4*)(base + (size_t)i * EE);
        float a = sAl[i];
        acc.x += a * v.x; acc.y += a * v.y; acc.z += a * v.z; acc.w += a * v.w;
    }
    *(float4*)&part[(size_t)(ts * 64 + b) * EE + tid * 4] = acc;
}

// ---------------- kernel 4: combine partials --------------------------------
__global__ void comb_k(const float* __restrict__ part, float* __restrict__ out) {
    int g = blockIdx.x * 256 + threadIdx.x;   // 0..65535
    float s = 0.f;
#pragma unroll
    for (int ts = 0; ts < 8; ++ts) s += part[(size_t)ts * 65536 + g];
    out[g] = s;
}

extern "C" void kernel_launch(void* const* d_in, const int* in_sizes, int n_in,
                              void* d_out, int out_size, void* d_ws, size_t ws_size,
                              hipStream_t stream) {
    const float* enc  = (const float*)d_in[0];
    const float* dec  = (const float*)d_in[1];
    const float* W    = (const float*)d_in[2];
    const float* bias = (const float*)d_in[3];
    const float* vw   = (const float*)d_in[4];
    float* out = (float*)d_out;

    char* ws = (char*)d_ws;
    short* wsWe   = (short*)(ws + OFF_WE);
    float* cbuf   = (float*)(ws + OFF_C);
    float* sp     = (float*)(ws + OFF_SP);
    float* alpha  = (float*)(ws + OFF_A);
    float* part   = (float*)(ws + OFF_P);

    prep_we_k<<<512, 256, 0, stream>>>(W, wsWe);
    prep_c_k<<<16384, 256, 0, stream>>>(W, bias, dec, cbuf);
    scores_k<<<dim3(32, 64), 512, 0, stream>>>(enc, wsWe, cbuf, vw, sp);
    softmax_k<<<64, 256, 0, stream>>>(sp, alpha);
    ctx_k<<<dim3(8, 64), 256, 0, stream>>>(enc, alpha, part);
    comb_k<<<256, 256, 0, stream>>>(part, out);
}

// Round 11
// 540.792 us; speedup vs baseline: 1.2981x; 1.2981x over previous
//
#include <hip/hip_runtime.h>
#include <hip/hip_bf16.h>
#include <cmath>

// Problem constants
#define BB 64
#define TT 2048
#define EE 1024
#define DD 1024
#define FAN 2048

typedef __attribute__((ext_vector_type(8))) short bhalf8;
typedef __attribute__((ext_vector_type(4))) float fvec4;

// ws layout (bytes)
#define OFF_WE   0u          // 2 MB  : We bf16, pre-swizzled [ec][eo][d][8]
#define OFF_C    2097152u    // 256 KB: c[b,d] = dec·Wd + bias
#define OFF_SP   2359296u    // 2 MB  : score partials [4 dq][64 b][2048 t]
#define OFF_A    4456448u    // 512 KB: alpha[b,t]
#define OFF_P    4980736u    // 2 MB  : context partials [8 ts][64 b][1024 e]

__device__ __forceinline__ short f2bf(float f) {
    unsigned int u = __float_as_uint(f);
    u += 0x7FFFu + ((u >> 16) & 1u);   // round-to-nearest-even
    return (short)(u >> 16);
}

__device__ __forceinline__ bhalf8 cvt8(float4 a, float4 b) {
    bhalf8 h;
    h[0] = f2bf(a.x); h[1] = f2bf(a.y); h[2] = f2bf(a.z); h[3] = f2bf(a.w);
    h[4] = f2bf(b.x); h[5] = f2bf(b.y); h[6] = f2bf(b.z); h[7] = f2bf(b.w);
    return h;
}

__device__ __forceinline__ float fast_tanhf(float x) {
    float ax = __builtin_fabsf(x);
    float e  = __expf(-2.0f * ax);
    float r  = (1.0f - e) * __builtin_amdgcn_rcpf(1.0f + e);
    return __builtin_copysignf(r, x);
}

// ---------------- kernel 0a: convert We (f32) -> pre-swizzled bf16 image ----
// image layout per 32-wide e-chunk ec: byte = ec*65536 + eo*16384 + d*16
__global__ void prep_we_k(const float* __restrict__ W, short* __restrict__ wsWe) {
    int g  = blockIdx.x * 256 + threadIdx.x;   // 0..131071
    int ec = g >> 12;          // 0..31
    int eo = (g >> 10) & 3;    // 0..3
    int d  = g & 1023;
    const float* src = W + (size_t)d * FAN + ec * 32 + eo * 8;
    float4 f0 = *(const float4*)src;
    float4 f1 = *(const float4*)(src + 4);
    *(bhalf8*)((char*)wsWe + (size_t)ec * 65536 + eo * 16384 + d * 16) = cvt8(f0, f1);
}

// ---------------- kernel 0b: c[b,d] = dec[b,:]·Wd[d,:] + bias[d] ------------
__global__ void prep_c_k(const float* __restrict__ W, const float* __restrict__ bias,
                         const float* __restrict__ dec, float* __restrict__ cbuf) {
    int wg   = blockIdx.x * 4 + (threadIdx.x >> 6);  // 0..65535
    int lane = threadIdx.x & 63;
    int b = wg >> 10, d = wg & 1023;
    const float* wrow = W + (size_t)d * FAN + EE;    // Wd part
    const float* drow = dec + b * DD;
    float p = 0.f;
#pragma unroll
    for (int i = 0; i < 16; ++i)
        p += wrow[i * 64 + lane] * drow[i * 64 + lane];
#pragma unroll
    for (int off = 1; off < 64; off <<= 1)
        p += __shfl_xor(p, off);
    if (lane == 0) cbuf[b * DD + d] = p + bias[d];
}

// ---------------- kernel 1: partial scores, OCCUPANCY build -----------------
// Tile 128t x 256d x BK=32. 8 waves (2m x 4n), wave-tile 64x64: acc = 64
// VGPR; __launch_bounds__(512,4) targets <=128 VGPR => 4 waves/SIMD =
// 2 INDEPENDENT blocks/CU (the lever rounds 4-10 never moved): one block's
// MFMAs cover the other's barrier/latency stalls (m114). Components are
// r4-proven: B register-direct from L2-resident image (0 conflicts), A
// staged reg->cvt->ds_write into [eo][t^(eo<<2)][8] (2-way max per 16-lane
// phase on write AND read), one __syncthreads per step. Partial v-dot into
// sp[dq] (deterministic).
__global__ __launch_bounds__(512, 4)
void scores_k(const float* __restrict__ enc, const short* __restrict__ wsWe,
              const float* __restrict__ cbuf, const float* __restrict__ vw,
              float* __restrict__ sp) {
    __shared__ short sA[2][4][128][8];  // 16 KB: [buf][eo][t^(eo<<2)][8e]
    __shared__ float sRed[8][64];       // 2 KB

    const int tid  = threadIdx.x;
    const int w    = tid >> 6;
    const int wm   = w >> 2;      // 0..1 (t half: 64 rows)
    const int wn   = w & 3;       // 0..3 (d slice: 64 cols)
    const int lane = tid & 63;
    const int lrow = lane >> 4;   // 0..3 (e-octet)
    const int lcol = lane & 15;
    const int b  = blockIdx.y;
    const int tt = blockIdx.x >> 2;     // 0..15
    const int dq = blockIdx.x & 3;      // 0..3 (low bits: same-A blocks adjacent)
    const int t0 = tt * 128;

    // staging: thread -> t row st (0..127), e-octet seo (0..3)
    const int st  = tid >> 2;
    const int seo = tid & 3;
    const int stw = st ^ (seo << 2);    // swizzled write row
    const float* gsrc = enc + ((size_t)(b * TT + t0 + st)) * EE + seo * 8;

    fvec4 acc[4][4];
#pragma unroll
    for (int m = 0; m < 4; ++m)
#pragma unroll
        for (int n = 0; n < 4; ++n)
            acc[m][n] = (fvec4){0.f, 0.f, 0.f, 0.f};

    // per-lane B base: eo=lrow, d = dq*256 + wn*64 + lcol
    const char* Bbase = (const char*)wsWe + lrow * 16384
                      + (size_t)(dq * 256 + wn * 64 + lcol) * 16;

    // prologue: stage chunk 0
    {
        float4 x0 = *(const float4*)(gsrc);
        float4 x1 = *(const float4*)(gsrc + 4);
        *(bhalf8*)&sA[0][seo][stw][0] = cvt8(x0, x1);
    }
    __syncthreads();

#pragma unroll 2
    for (int i = 0; i < 32; ++i) {
        const int buf = i & 1;
        // (1) register prefetch of fp32 A chunk i+1
        float4 x0, x1;
        if (i < 31) {
            x0 = *(const float4*)(gsrc + (i + 1) * 32);
            x1 = *(const float4*)(gsrc + (i + 1) * 32 + 4);
        }
        // (2) B frags for this k-slice (L2 register-direct)
        bhalf8 bf[4];
#pragma unroll
        for (int n = 0; n < 4; ++n)
            bf[n] = *(const bhalf8*)(Bbase + (size_t)i * 65536 + n * 256);
        // (3) A frags from LDS
        bhalf8 af[4];
#pragma unroll
        for (int m = 0; m < 4; ++m) {
            int t = wm * 64 + m * 16 + lcol;
            af[m] = *(const bhalf8*)&sA[buf][lrow][t ^ (lrow << 2)][0];
        }
        // (4) 16 MFMA
#pragma unroll
        for (int n = 0; n < 4; ++n)
#pragma unroll
            for (int m = 0; m < 4; ++m)
                acc[m][n] = __builtin_amdgcn_mfma_f32_16x16x32_bf16(af[m], bf[n], acc[m][n], 0, 0, 0);
        // (5) cvt + swizzled write of chunk i+1
        if (i < 31)
            *(bhalf8*)&sA[buf ^ 1][seo][stw][0] = cvt8(x0, x1);
        __syncthreads();
    }

    float cv[4], vv[4];
#pragma unroll
    for (int n = 0; n < 4; ++n) {
        int d = dq * 256 + wn * 64 + n * 16 + lcol;
        cv[n] = cbuf[b * DD + d];
        vv[n] = vw[d];
    }

    // epilogue: tanh + partial v-dot over this wave's 64 d's
#pragma unroll
    for (int m = 0; m < 4; ++m) {
#pragma unroll
        for (int j = 0; j < 4; ++j) {
            float p = 0.f;
#pragma unroll
            for (int n = 0; n < 4; ++n)
                p += vv[n] * fast_tanhf(acc[m][n][j] + cv[n]);
            p += __shfl_xor(p, 1); p += __shfl_xor(p, 2);
            p += __shfl_xor(p, 4); p += __shfl_xor(p, 8);
            if (lcol == 0) sRed[w][m * 16 + lrow * 4 + j] = p;
        }
    }
    __syncthreads();
    if (tid < 128) {
        int r  = tid;                 // 0..127 within t-tile
        int rm = r >> 6, lr = r & 63;
        float v2 = sRed[rm * 4 + 0][lr] + sRed[rm * 4 + 1][lr]
                 + sRed[rm * 4 + 2][lr] + sRed[rm * 4 + 3][lr];
        sp[((size_t)dq * BB + b) * TT + t0 + r] = v2;
    }
}

// ---------------- kernel 2: sum partials + softmax over t per batch ---------
__global__ void softmax_k(const float* __restrict__ sp, float* __restrict__ alpha) {
    int b = blockIdx.x, tid = threadIdx.x;
    float s[8];
    float m = -1e30f;
#pragma unroll
    for (int i = 0; i < 8; ++i) {
        size_t idx = (size_t)b * TT + i * 256 + tid;
        s[i] = sp[idx] + sp[(size_t)BB * TT + idx]
             + sp[2 * (size_t)BB * TT + idx] + sp[3 * (size_t)BB * TT + idx];
        m = fmaxf(m, s[i]);
    }
#pragma unroll
    for (int off = 1; off < 64; off <<= 1) m = fmaxf(m, __shfl_xor(m, off));
    __shared__ float red[4], red2[4];
    if ((tid & 63) == 0) red[tid >> 6] = m;
    __syncthreads();
    m = fmaxf(fmaxf(red[0], red[1]), fmaxf(red[2], red[3]));
    float sum = 0.f;
#pragma unroll
    for (int i = 0; i < 8; ++i) { s[i] = expf(s[i] - m); sum += s[i]; }
#pragma unroll
    for (int off = 1; off < 64; off <<= 1) sum += __shfl_xor(sum, off);
    if ((tid & 63) == 0) red2[tid >> 6] = sum;
    __syncthreads();
    sum = red2[0] + red2[1] + red2[2] + red2[3];
    float inv = 1.0f / sum;
#pragma unroll
    for (int i = 0; i < 8; ++i) alpha[b * TT + i * 256 + tid] = s[i] * inv;
}

// ---------------- kernel 3: context partials over t-slices ------------------
__global__ void ctx_k(const float* __restrict__ enc, const float* __restrict__ alpha,
                      float* __restrict__ part) {
    int ts = blockIdx.x, b = blockIdx.y, tid = threadIdx.x;
    __shared__ float sAl[256];
    sAl[tid] = alpha[b * TT + ts * 256 + tid];
    __syncthreads();
    float4 acc = {0.f, 0.f, 0.f, 0.f};
    const float* base = enc + ((size_t)b * TT + ts * 256) * EE + tid * 4;
#pragma unroll 8
    for (int i = 0; i < 256; ++i) {
        float4 v = *(const float4*)(base + (size_t)i * EE);
        float a = sAl[i];
        acc.x += a * v.x; acc.y += a * v.y; acc.z += a * v.z; acc.w += a * v.w;
    }
    *(float4*)&part[(size_t)(ts * 64 + b) * EE + tid * 4] = acc;
}

// ---------------- kernel 4: combine partials --------------------------------
__global__ void comb_k(const float* __restrict__ part, float* __restrict__ out) {
    int g = blockIdx.x * 256 + threadIdx.x;   // 0..65535
    float s = 0.f;
#pragma unroll
    for (int ts = 0; ts < 8; ++ts) s += part[(size_t)ts * 65536 + g];
    out[g] = s;
}

extern "C" void kernel_launch(void* const* d_in, const int* in_sizes, int n_in,
                              void* d_out, int out_size, void* d_ws, size_t ws_size,
                              hipStream_t stream) {
    const float* enc  = (const float*)d_in[0];
    const float* dec  = (const float*)d_in[1];
    const float* W    = (const float*)d_in[2];
    const float* bias = (const float*)d_in[3];
    const float* vw   = (const float*)d_in[4];
    float* out = (float*)d_out;

    char* ws = (char*)d_ws;
    short* wsWe   = (short*)(ws + OFF_WE);
    float* cbuf   = (float*)(ws + OFF_C);
    float* sp     = (float*)(ws + OFF_SP);
    float* alpha  = (float*)(ws + OFF_A);
    float* part   = (float*)(ws + OFF_P);

    prep_we_k<<<512, 256, 0, stream>>>(W, wsWe);
    prep_c_k<<<16384, 256, 0, stream>>>(W, bias, dec, cbuf);
    scores_k<<<dim3(64, 64), 512, 0, stream>>>(enc, wsWe, cbuf, vw, sp);
    softmax_k<<<64, 256, 0, stream>>>(sp, alpha);
    ctx_k<<<dim3(8, 64), 256, 0, stream>>>(enc, alpha, part);
    comb_k<<<256, 256, 0, stream>>>(part, out);
}

// Round 12
// 532.059 us; speedup vs baseline: 1.3194x; 1.0164x over previous
//
#include <hip/hip_runtime.h>
#include <hip/hip_bf16.h>
#include <cmath>

// Problem constants
#define BB 64
#define TT 2048
#define EE 1024
#define DD 1024
#define FAN 2048

typedef __attribute__((ext_vector_type(8))) short bhalf8;
typedef __attribute__((ext_vector_type(4))) float fvec4;

// ws layout (bytes)
#define OFF_WE   0u          // 2 MB  : We bf16, pre-swizzled [ec][eo][d][8]
#define OFF_C    2097152u    // 256 KB: c[b,d] = dec·Wd + bias
#define OFF_SP   2359296u    // 2 MB  : score partials [4 dq][64 b][2048 t]
#define OFF_A    4456448u    // 512 KB: alpha[b,t]
#define OFF_P    4980736u    // 2 MB  : context partials [8 ts][64 b][1024 e]
#define OFF_ENCB 8388608u    // 256 MB: enc bf16 row-major [b*T+t][e]
#define WS_NEED  (OFF_ENCB + (size_t)BB * TT * EE * 2)

__device__ __forceinline__ short f2bf(float f) {
    unsigned int u = __float_as_uint(f);
    u += 0x7FFFu + ((u >> 16) & 1u);   // round-to-nearest-even
    return (short)(u >> 16);
}

__device__ __forceinline__ bhalf8 cvt8(float4 a, float4 b) {
    bhalf8 h;
    h[0] = f2bf(a.x); h[1] = f2bf(a.y); h[2] = f2bf(a.z); h[3] = f2bf(a.w);
    h[4] = f2bf(b.x); h[5] = f2bf(b.y); h[6] = f2bf(b.z); h[7] = f2bf(b.w);
    return h;
}

__device__ __forceinline__ float fast_tanhf(float x) {
    float ax = __builtin_fabsf(x);
    float e  = __expf(-2.0f * ax);
    float r  = (1.0f - e) * __builtin_amdgcn_rcpf(1.0f + e);
    return __builtin_copysignf(r, x);
}

__device__ __forceinline__ void dma16(const void* g, void* l) {
    __builtin_amdgcn_global_load_lds(
        (const __attribute__((address_space(1))) void*)g,
        (__attribute__((address_space(3))) void*)l,
        16, 0, 0);
}

// ---------------- kernel 0a: We (f32) -> pre-swizzled bf16 image ------------
__global__ void prep_we_k(const float* __restrict__ W, short* __restrict__ wsWe) {
    int g  = blockIdx.x * 256 + threadIdx.x;   // 0..131071
    int ec = g >> 12;
    int eo = (g >> 10) & 3;
    int d  = g & 1023;
    const float* src = W + (size_t)d * FAN + ec * 32 + eo * 8;
    float4 f0 = *(const float4*)src;
    float4 f1 = *(const float4*)(src + 4);
    *(bhalf8*)((char*)wsWe + (size_t)ec * 65536 + eo * 16384 + d * 16) = cvt8(f0, f1);
}

// ---------------- kernel 0b: c[b,d] = dec[b,:]·Wd[d,:] + bias[d] ------------
__global__ void prep_c_k(const float* __restrict__ W, const float* __restrict__ bias,
                         const float* __restrict__ dec, float* __restrict__ cbuf) {
    int wg   = blockIdx.x * 4 + (threadIdx.x >> 6);
    int lane = threadIdx.x & 63;
    int b = wg >> 10, d = wg & 1023;
    const float* wrow = W + (size_t)d * FAN + EE;
    const float* drow = dec + b * DD;
    float p = 0.f;
#pragma unroll
    for (int i = 0; i < 16; ++i)
        p += wrow[i * 64 + lane] * drow[i * 64 + lane];
#pragma unroll
    for (int off = 1; off < 64; off <<= 1)
        p += __shfl_xor(p, off);
    if (lane == 0) cbuf[b * DD + d] = p + bias[d];
}

// ---------------- kernel 0c: enc f32 -> bf16, pure streaming copy -----------
__global__ void prep_encb_k(const float* __restrict__ enc, short* __restrict__ encB) {
    size_t g = (size_t)blockIdx.x * 256 + threadIdx.x;   // 0..16777215
    const float* src = enc + g * 8;
    float4 f0 = *(const float4*)src;
    float4 f1 = *(const float4*)(src + 4);
    *(bhalf8*)(encB + g * 8) = cvt8(f0, f1);
}

// ---------------- kernel 1 (new): lean bf16 GEMM, counted-vmcnt pipeline ----
// Tile 128t x 256d x BK=64, 16 iters. 8 waves (2m x 4n), wave 64x64, acc=64.
// A: bf16 encB via global_load_lds DMA, 3 slabs x 16 KB, depth-2 issue,
//    chunk swizzle slot = t*8 + (xi ^ (t&7)) => conflict-free b128 reads.
// B: register-direct from L2-resident We image, half-iter-ahead dbuf (r4).
// End-of-iter: s_waitcnt vmcnt(6) (A(i+2) DMA + next bfA stay in flight),
// raw s_barrier — never drain to 0 in the loop (T4). setprio on MFMA (T5).
__global__ __launch_bounds__(512, 4)
void scores_k(const short* __restrict__ encB, const short* __restrict__ wsWe,
              const float* __restrict__ cbuf, const float* __restrict__ vw,
              float* __restrict__ sp) {
    __shared__ __align__(16) short smA[3][8192];   // 3 x 16 KB
    __shared__ float sRed[8][64];                  // 2 KB

    const int tid  = threadIdx.x;
    const int w    = tid >> 6;
    const int wm   = w >> 2;      // 0..1
    const int wn   = w & 3;       // 0..3
    const int lane = tid & 63;
    const int lrow = lane >> 4;   // 0..3
    const int lcol = lane & 15;
    const int b  = blockIdx.y;
    const int tt = blockIdx.x >> 2;     // 0..15
    const int dq = blockIdx.x & 3;      // 0..3
    const int t0 = tt * 128;

    // A-DMA mapping: op j in {0,1}: slot = tid + j*512; t = slot>>3 (=tJ+64j),
    // xi_slot = slot&7, xi_global = xi_slot ^ (t&7)  ((t+64)&7 == t&7)
    const int tJ = tid >> 3;
    const int xg = (tid & 7) ^ (tJ & 7);
    const char* gA = (const char*)encB + ((size_t)(b * TT + t0 + tJ)) * 2048 + xg * 16;

    // B per-lane base: eo=lrow, d = dq*256 + wn*64 + lcol
    const char* Bbase = (const char*)wsWe + lrow * 16384
                      + (size_t)(dq * 256 + wn * 64 + lcol) * 16;

    fvec4 acc[4][4];
#pragma unroll
    for (int m = 0; m < 4; ++m)
#pragma unroll
        for (int n = 0; n < 4; ++n)
            acc[m][n] = (fvec4){0.f, 0.f, 0.f, 0.f};

    // A-frag swizzled chunk offsets (xi = kk*4 + lrow)
    const int ax0 = ((lrow)     ^ (lcol & 7)) * 16;
    const int ax1 = ((4 + lrow) ^ (lcol & 7)) * 16;
    const int tb0 = (wm * 64 + lcol) * 128;        // + m*2048 per frag

    bhalf8 bfA[4], bfB[4];

#define DMA_TILE(K, S)                                                        \
    do {                                                                      \
        dma16(gA + (size_t)(K) * 128,          (char*)smA[(S)] + tid * 16);   \
        dma16(gA + 131072 + (size_t)(K) * 128, (char*)smA[(S)] + tid * 16 + 8192); \
    } while (0)

    // prologue: A(0)->s0, A(1)->s1, bfA = B(ks=0); wait A(0); barrier
    DMA_TILE(0, 0);
    DMA_TILE(1, 1);
#pragma unroll
    for (int n = 0; n < 4; ++n)
        bfA[n] = *(const bhalf8*)(Bbase + n * 256);
    asm volatile("s_waitcnt vmcnt(6)" ::: "memory");
    __builtin_amdgcn_s_barrier();

#define STEP(I, S, SS, DOSTAGE, DOPRE)                                        \
    do {                                                                      \
        if (DOSTAGE) DMA_TILE((I) + 2, SS);                                   \
        /* kk0 */                                                             \
        {                                                                     \
            _Pragma("unroll")                                                 \
            for (int n = 0; n < 4; ++n)                                       \
                bfB[n] = *(const bhalf8*)(Bbase                               \
                          + (size_t)(2 * (I) + 1) * 65536 + n * 256);         \
            bhalf8 af[4];                                                     \
            _Pragma("unroll")                                                 \
            for (int m = 0; m < 4; ++m)                                       \
                af[m] = *(const bhalf8*)((const char*)smA[(S)]                \
                          + tb0 + m * 2048 + ax0);                            \
            __builtin_amdgcn_s_setprio(1);                                    \
            _Pragma("unroll")                                                 \
            for (int n = 0; n < 4; ++n)                                       \
                _Pragma("unroll")                                             \
                for (int m = 0; m < 4; ++m)                                   \
                    acc[m][n] = __builtin_amdgcn_mfma_f32_16x16x32_bf16(      \
                        af[m], bfA[n], acc[m][n], 0, 0, 0);                   \
            __builtin_amdgcn_s_setprio(0);                                    \
        }                                                                     \
        /* kk1 */                                                             \
        {                                                                     \
            if (DOPRE) {                                                      \
                _Pragma("unroll")                                             \
                for (int n = 0; n < 4; ++n)                                   \
                    bfA[n] = *(const bhalf8*)(Bbase                           \
                              + (size_t)(2 * (I) + 2) * 65536 + n * 256);     \
            }                                                                 \
            bhalf8 af[4];                                                     \
            _Pragma("unroll")                                                 \
            for (int m = 0; m < 4; ++m)                                       \
                af[m] = *(const bhalf8*)((const char*)smA[(S)]                \
                          + tb0 + m * 2048 + ax1);                            \
            __builtin_amdgcn_s_setprio(1);                                    \
            _Pragma("unroll")                                                 \
            for (int n = 0; n < 4; ++n)                                       \
                _Pragma("unroll")                                             \
                for (int m = 0; m < 4; ++m)                                   \
                    acc[m][n] = __builtin_amdgcn_mfma_f32_16x16x32_bf16(      \
                        af[m], bfB[n], acc[m][n], 0, 0, 0);                   \
            __builtin_amdgcn_s_setprio(0);                                    \
        }                                                                     \
    } while (0)

#define WB(N)                                                                 \
    do {                                                                      \
        asm volatile("s_waitcnt vmcnt(" #N ")" ::: "memory");                 \
        __builtin_amdgcn_s_barrier();                                         \
    } while (0)

    STEP(0, 0, 2, 1, 1);  WB(6);
    STEP(1, 1, 0, 1, 1);  WB(6);
    STEP(2, 2, 1, 1, 1);  WB(6);
    STEP(3, 0, 2, 1, 1);  WB(6);
    STEP(4, 1, 0, 1, 1);  WB(6);
    STEP(5, 2, 1, 1, 1);  WB(6);
    STEP(6, 0, 2, 1, 1);  WB(6);
    STEP(7, 1, 0, 1, 1);  WB(6);
    STEP(8, 2, 1, 1, 1);  WB(6);
    STEP(9, 0, 2, 1, 1);  WB(6);
    STEP(10, 1, 0, 1, 1); WB(6);
    STEP(11, 2, 1, 1, 1); WB(6);
    STEP(12, 0, 2, 1, 1); WB(6);
    STEP(13, 1, 0, 1, 1); WB(6);
    STEP(14, 2, 0, 0, 1); WB(4);
    STEP(15, 0, 0, 0, 0);
#undef STEP
#undef WB
#undef DMA_TILE

    float cv[4], vv[4];
#pragma unroll
    for (int n = 0; n < 4; ++n) {
        int d = dq * 256 + wn * 64 + n * 16 + lcol;
        cv[n] = cbuf[b * DD + d];
        vv[n] = vw[d];
    }

    // epilogue: tanh + partial v-dot over this wave's 64 d's
#pragma unroll
    for (int m = 0; m < 4; ++m) {
#pragma unroll
        for (int j = 0; j < 4; ++j) {
            float p = 0.f;
#pragma unroll
            for (int n = 0; n < 4; ++n)
                p += vv[n] * fast_tanhf(acc[m][n][j] + cv[n]);
            p += __shfl_xor(p, 1); p += __shfl_xor(p, 2);
            p += __shfl_xor(p, 4); p += __shfl_xor(p, 8);
            if (lcol == 0) sRed[w][m * 16 + lrow * 4 + j] = p;
        }
    }
    __syncthreads();
    if (tid < 128) {
        int r  = tid;
        int rm = r >> 6, lr = r & 63;
        float v2 = sRed[rm * 4 + 0][lr] + sRed[rm * 4 + 1][lr]
                 + sRed[rm * 4 + 2][lr] + sRed[rm * 4 + 3][lr];
        sp[((size_t)dq * BB + b) * TT + t0 + r] = v2;
    }
}

// ---------------- kernel 1-fallback: r11 scores (if ws too small) -----------
__global__ __launch_bounds__(512, 4)
void scores_fb_k(const float* __restrict__ enc, const short* __restrict__ wsWe,
                 const float* __restrict__ cbuf, const float* __restrict__ vw,
                 float* __restrict__ sp) {
    __shared__ short sA[2][4][128][8];
    __shared__ float sRed[8][64];
    const int tid  = threadIdx.x;
    const int w    = tid >> 6;
    const int wm   = w >> 2;
    const int wn   = w & 3;
    const int lane = tid & 63;
    const int lrow = lane >> 4;
    const int lcol = lane & 15;
    const int b  = blockIdx.y;
    const int tt = blockIdx.x >> 2;
    const int dq = blockIdx.x & 3;
    const int t0 = tt * 128;
    const int st  = tid >> 2;
    const int seo = tid & 3;
    const int stw = st ^ (seo << 2);
    const float* gsrc = enc + ((size_t)(b * TT + t0 + st)) * EE + seo * 8;
    fvec4 acc[4][4];
#pragma unroll
    for (int m = 0; m < 4; ++m)
#pragma unroll
        for (int n = 0; n < 4; ++n)
            acc[m][n] = (fvec4){0.f, 0.f, 0.f, 0.f};
    const char* Bbase = (const char*)wsWe + lrow * 16384
                      + (size_t)(dq * 256 + wn * 64 + lcol) * 16;
    {
        float4 x0 = *(const float4*)(gsrc);
        float4 x1 = *(const float4*)(gsrc + 4);
        *(bhalf8*)&sA[0][seo][stw][0] = cvt8(x0, x1);
    }
    __syncthreads();
#pragma unroll 2
    for (int i = 0; i < 32; ++i) {
        const int buf = i & 1;
        float4 x0, x1;
        if (i < 31) {
            x0 = *(const float4*)(gsrc + (i + 1) * 32);
            x1 = *(const float4*)(gsrc + (i + 1) * 32 + 4);
        }
        bhalf8 bf[4];
#pragma unroll
        for (int n = 0; n < 4; ++n)
            bf[n] = *(const bhalf8*)(Bbase + (size_t)i * 65536 + n * 256);
        bhalf8 af[4];
#pragma unroll
        for (int m = 0; m < 4; ++m) {
            int t = wm * 64 + m * 16 + lcol;
            af[m] = *(const bhalf8*)&sA[buf][lrow][t ^ (lrow << 2)][0];
        }
#pragma unroll
        for (int n = 0; n < 4; ++n)
#pragma unroll
            for (int m = 0; m < 4; ++m)
                acc[m][n] = __builtin_amdgcn_mfma_f32_16x16x32_bf16(af[m], bf[n], acc[m][n], 0, 0, 0);
        if (i < 31)
            *(bhalf8*)&sA[buf ^ 1][seo][stw][0] = cvt8(x0, x1);
        __syncthreads();
    }
    float cv[4], vv[4];
#pragma unroll
    for (int n = 0; n < 4; ++n) {
        int d = dq * 256 + wn * 64 + n * 16 + lcol;
        cv[n] = cbuf[b * DD + d];
        vv[n] = vw[d];
    }
#pragma unroll
    for (int m = 0; m < 4; ++m) {
#pragma unroll
        for (int j = 0; j < 4; ++j) {
            float p = 0.f;
#pragma unroll
            for (int n = 0; n < 4; ++n)
                p += vv[n] * fast_tanhf(acc[m][n][j] + cv[n]);
            p += __shfl_xor(p, 1); p += __shfl_xor(p, 2);
            p += __shfl_xor(p, 4); p += __shfl_xor(p, 8);
            if (lcol == 0) sRed[w][m * 16 + lrow * 4 + j] = p;
        }
    }
    __syncthreads();
    if (tid < 128) {
        int r  = tid;
        int rm = r >> 6, lr = r & 63;
        float v2 = sRed[rm * 4 + 0][lr] + sRed[rm * 4 + 1][lr]
                 + sRed[rm * 4 + 2][lr] + sRed[rm * 4 + 3][lr];
        sp[((size_t)dq * BB + b) * TT + t0 + r] = v2;
    }
}

// ---------------- kernel 2: sum partials + softmax over t per batch ---------
__global__ void softmax_k(const float* __restrict__ sp, float* __restrict__ alpha) {
    int b = blockIdx.x, tid = threadIdx.x;
    float s[8];
    float m = -1e30f;
#pragma unroll
    for (int i = 0; i < 8; ++i) {
        size_t idx = (size_t)b * TT + i * 256 + tid;
        s[i] = sp[idx] + sp[(size_t)BB * TT + idx]
             + sp[2 * (size_t)BB * TT + idx] + sp[3 * (size_t)BB * TT + idx];
        m = fmaxf(m, s[i]);
    }
#pragma unroll
    for (int off = 1; off < 64; off <<= 1) m = fmaxf(m, __shfl_xor(m, off));
    __shared__ float red[4], red2[4];
    if ((tid & 63) == 0) red[tid >> 6] = m;
    __syncthreads();
    m = fmaxf(fmaxf(red[0], red[1]), fmaxf(red[2], red[3]));
    float sum = 0.f;
#pragma unroll
    for (int i = 0; i < 8; ++i) { s[i] = expf(s[i] - m); sum += s[i]; }
#pragma unroll
    for (int off = 1; off < 64; off <<= 1) sum += __shfl_xor(sum, off);
    if ((tid & 63) == 0) red2[tid >> 6] = sum;
    __syncthreads();
    sum = red2[0] + red2[1] + red2[2] + red2[3];
    float inv = 1.0f / sum;
#pragma unroll
    for (int i = 0; i < 8; ++i) alpha[b * TT + i * 256 + tid] = s[i] * inv;
}

// ---------------- kernel 3: context partials over t-slices ------------------
__global__ void ctx_k(const float* __restrict__ enc, const float* __restrict__ alpha,
                      float* __restrict__ part) {
    int ts = blockIdx.x, b = blockIdx.y, tid = threadIdx.x;
    __shared__ float sAl[256];
    sAl[tid] = alpha[b * TT + ts * 256 + tid];
    __syncthreads();
    float4 acc = {0.f, 0.f, 0.f, 0.f};
    const float* base = enc + ((size_t)b * TT + ts * 256) * EE + tid * 4;
#pragma unroll 8
    for (int i = 0; i < 256; ++i) {
        float4 v = *(const float4*)(base + (size_t)i * EE);
        float a = sAl[i];
        acc.x += a * v.x; acc.y += a * v.y; acc.z += a * v.z; acc.w += a * v.w;
    }
    *(float4*)&part[(size_t)(ts * 64 + b) * EE + tid * 4] = acc;
}

// ---------------- kernel 4: combine partials --------------------------------
__global__ void comb_k(const float* __restrict__ part, float* __restrict__ out) {
    int g = blockIdx.x * 256 + threadIdx.x;
    float s = 0.f;
#pragma unroll
    for (int ts = 0; ts < 8; ++ts) s += part[(size_t)ts * 65536 + g];
    out[g] = s;
}

extern "C" void kernel_launch(void* const* d_in, const int* in_sizes, int n_in,
                              void* d_out, int out_size, void* d_ws, size_t ws_size,
                              hipStream_t stream) {
    const float* enc  = (const float*)d_in[0];
    const float* dec  = (const float*)d_in[1];
    const float* W    = (const float*)d_in[2];
    const float* bias = (const float*)d_in[3];
    const float* vw   = (const float*)d_in[4];
    float* out = (float*)d_out;

    char* ws = (char*)d_ws;
    short* wsWe   = (short*)(ws + OFF_WE);
    float* cbuf   = (float*)(ws + OFF_C);
    float* sp     = (float*)(ws + OFF_SP);
    float* alpha  = (float*)(ws + OFF_A);
    float* part   = (float*)(ws + OFF_P);
    short* encB   = (short*)(ws + OFF_ENCB);

    prep_we_k<<<512, 256, 0, stream>>>(W, wsWe);
    prep_c_k<<<16384, 256, 0, stream>>>(W, bias, dec, cbuf);
    if (ws_size >= WS_NEED) {
        prep_encb_k<<<65536, 256, 0, stream>>>(enc, encB);
        scores_k<<<dim3(64, 64), 512, 0, stream>>>(encB, wsWe, cbuf, vw, sp);
    } else {
        scores_fb_k<<<dim3(64, 64), 512, 0, stream>>>(enc, wsWe, cbuf, vw, sp);
    }
    softmax_k<<<64, 256, 0, stream>>>(sp, alpha);
    ctx_k<<<dim3(8, 64), 256, 0, stream>>>(enc, alpha, part);
    comb_k<<<256, 256, 0, stream>>>(part, out);
}

// Round 13
// 514.477 us; speedup vs baseline: 1.3644x; 1.0342x over previous
//
#include <hip/hip_runtime.h>
#include <hip/hip_bf16.h>
#include <cmath>

// Problem constants
#define BB 64
#define TT 2048
#define EE 1024
#define DD 1024
#define FAN 2048

typedef __attribute__((ext_vector_type(8))) short bhalf8;
typedef __attribute__((ext_vector_type(4))) float fvec4;

// ws layout (bytes)
#define OFF_WE   0u          // 2 MB  : We bf16, pre-swizzled [ec][eo][d][8]
#define OFF_C    2097152u    // 256 KB: c[b,d] = dec·Wd + bias
#define OFF_SP   2359296u    // 2 MB  : score partials [4 dq][64 b][2048 t]
#define OFF_A    4456448u    // 512 KB: alpha[b,t]
#define OFF_P    4980736u    // 4 MB  : context partials [16 ts][64 b][1024 e]
#define OFF_ENCB 16777216u   // 256 MB: enc bf16 row-major [b*T+t][e]
#define WS_NEED  (OFF_ENCB + (size_t)BB * TT * EE * 2)

__device__ __forceinline__ short f2bf(float f) {
    unsigned int u = __float_as_uint(f);
    u += 0x7FFFu + ((u >> 16) & 1u);   // round-to-nearest-even
    return (short)(u >> 16);
}

__device__ __forceinline__ float bf2f(short s) {
    unsigned int u = ((unsigned int)(unsigned short)s) << 16;
    return __uint_as_float(u);
}

__device__ __forceinline__ bhalf8 cvt8(float4 a, float4 b) {
    bhalf8 h;
    h[0] = f2bf(a.x); h[1] = f2bf(a.y); h[2] = f2bf(a.z); h[3] = f2bf(a.w);
    h[4] = f2bf(b.x); h[5] = f2bf(b.y); h[6] = f2bf(b.z); h[7] = f2bf(b.w);
    return h;
}

__device__ __forceinline__ float fast_tanhf(float x) {
    float ax = __builtin_fabsf(x);
    float e  = __expf(-2.0f * ax);
    float r  = (1.0f - e) * __builtin_amdgcn_rcpf(1.0f + e);
    return __builtin_copysignf(r, x);
}

__device__ __forceinline__ void dma16(const void* g, void* l) {
    __builtin_amdgcn_global_load_lds(
        (const __attribute__((address_space(1))) void*)g,
        (__attribute__((address_space(3))) void*)l,
        16, 0, 0);
}

// ---------------- kernel 0a: We (f32) -> pre-swizzled bf16 image ------------
__global__ void prep_we_k(const float* __restrict__ W, short* __restrict__ wsWe) {
    int g  = blockIdx.x * 256 + threadIdx.x;   // 0..131071
    int ec = g >> 12;
    int eo = (g >> 10) & 3;
    int d  = g & 1023;
    const float* src = W + (size_t)d * FAN + ec * 32 + eo * 8;
    float4 f0 = *(const float4*)src;
    float4 f1 = *(const float4*)(src + 4);
    *(bhalf8*)((char*)wsWe + (size_t)ec * 65536 + eo * 16384 + d * 16) = cvt8(f0, f1);
}

// ---------------- kernel 0b: c[b,d] = dec[b,:]·Wd[d,:] + bias[d] ------------
// LDS-tiled: W read exactly ONCE (4 MB total, was 268 MB). grid 64 blocks
// (16 d each), 256 thr: thread owns b=tid>>2, 4 d's = (tid&3)*4..+4.
__global__ __launch_bounds__(256)
void prep_c_k(const float* __restrict__ W, const float* __restrict__ bias,
              const float* __restrict__ dec, float* __restrict__ cbuf) {
    __shared__ float wd[16][68];   // chunk [dl][e], stride 68 (272B, 16-aligned)
    __shared__ float dc[64][68];
    const int tid = threadIdx.x;
    const int d0  = blockIdx.x * 16;
    const int b   = tid >> 2;
    const int dg  = tid & 3;
    float acc[4] = {0.f, 0.f, 0.f, 0.f};
    const int r  = tid >> 2;           // staging row
    const int c4 = (tid & 3) * 16;     // staging col (16 floats)
    for (int ec = 0; ec < 16; ++ec) {
        if (tid < 64) {
            const float* ws = W + (size_t)(d0 + r) * FAN + EE + ec * 64 + c4;
#pragma unroll
            for (int q = 0; q < 4; ++q)
                *(float4*)&wd[r][c4 + q * 4] = *(const float4*)(ws + q * 4);
        }
        {
            const float* ds = dec + (size_t)r * DD + ec * 64 + c4;
#pragma unroll
            for (int q = 0; q < 4; ++q)
                *(float4*)&dc[r][c4 + q * 4] = *(const float4*)(ds + q * 4);
        }
        __syncthreads();
#pragma unroll 4
        for (int e = 0; e < 64; e += 4) {
            float4 dv = *(const float4*)&dc[b][e];
#pragma unroll
            for (int i = 0; i < 4; ++i) {
                float4 wv = *(const float4*)&wd[dg * 4 + i][e];
                acc[i] += wv.x * dv.x + wv.y * dv.y + wv.z * dv.z + wv.w * dv.w;
            }
        }
        __syncthreads();
    }
#pragma unroll
    for (int i = 0; i < 4; ++i) {
        int d = d0 + dg * 4 + i;
        cbuf[b * DD + d] = acc[i] + bias[d];
    }
}

// ---------------- kernel 0c: enc f32 -> bf16, pure streaming copy -----------
__global__ void prep_encb_k(const float* __restrict__ enc, short* __restrict__ encB) {
    size_t g = (size_t)blockIdx.x * 256 + threadIdx.x;   // 0..16777215
    const float* src = enc + g * 8;
    float4 f0 = *(const float4*)src;
    float4 f1 = *(const float4*)(src + 4);
    *(bhalf8*)(encB + g * 8) = cvt8(f0, f1);
}

// ---------------- kernel 1: lean bf16 GEMM, counted-vmcnt pipeline ----------
// (byte-identical to r12 — measured ~50% of MFMA floor, leave alone)
__global__ __launch_bounds__(512, 4)
void scores_k(const short* __restrict__ encB, const short* __restrict__ wsWe,
              const float* __restrict__ cbuf, const float* __restrict__ vw,
              float* __restrict__ sp) {
    __shared__ __align__(16) short smA[3][8192];   // 3 x 16 KB
    __shared__ float sRed[8][64];                  // 2 KB

    const int tid  = threadIdx.x;
    const int w    = tid >> 6;
    const int wm   = w >> 2;      // 0..1
    const int wn   = w & 3;       // 0..3
    const int lane = tid & 63;
    const int lrow = lane >> 4;   // 0..3
    const int lcol = lane & 15;
    const int b  = blockIdx.y;
    const int tt = blockIdx.x >> 2;     // 0..15
    const int dq = blockIdx.x & 3;      // 0..3
    const int t0 = tt * 128;

    const int tJ = tid >> 3;
    const int xg = (tid & 7) ^ (tJ & 7);
    const char* gA = (const char*)encB + ((size_t)(b * TT + t0 + tJ)) * 2048 + xg * 16;

    const char* Bbase = (const char*)wsWe + lrow * 16384
                      + (size_t)(dq * 256 + wn * 64 + lcol) * 16;

    fvec4 acc[4][4];
#pragma unroll
    for (int m = 0; m < 4; ++m)
#pragma unroll
        for (int n = 0; n < 4; ++n)
            acc[m][n] = (fvec4){0.f, 0.f, 0.f, 0.f};

    const int ax0 = ((lrow)     ^ (lcol & 7)) * 16;
    const int ax1 = ((4 + lrow) ^ (lcol & 7)) * 16;
    const int tb0 = (wm * 64 + lcol) * 128;

    bhalf8 bfA[4], bfB[4];

#define DMA_TILE(K, S)                                                        \
    do {                                                                      \
        dma16(gA + (size_t)(K) * 128,          (char*)smA[(S)] + tid * 16);   \
        dma16(gA + 131072 + (size_t)(K) * 128, (char*)smA[(S)] + tid * 16 + 8192); \
    } while (0)

    DMA_TILE(0, 0);
    DMA_TILE(1, 1);
#pragma unroll
    for (int n = 0; n < 4; ++n)
        bfA[n] = *(const bhalf8*)(Bbase + n * 256);
    asm volatile("s_waitcnt vmcnt(6)" ::: "memory");
    __builtin_amdgcn_s_barrier();

#define STEP(I, S, SS, DOSTAGE, DOPRE)                                        \
    do {                                                                      \
        if (DOSTAGE) DMA_TILE((I) + 2, SS);                                   \
        {                                                                     \
            _Pragma("unroll")                                                 \
            for (int n = 0; n < 4; ++n)                                       \
                bfB[n] = *(const bhalf8*)(Bbase                               \
                          + (size_t)(2 * (I) + 1) * 65536 + n * 256);         \
            bhalf8 af[4];                                                     \
            _Pragma("unroll")                                                 \
            for (int m = 0; m < 4; ++m)                                       \
                af[m] = *(const bhalf8*)((const char*)smA[(S)]                \
                          + tb0 + m * 2048 + ax0);                            \
            __builtin_amdgcn_s_setprio(1);                                    \
            _Pragma("unroll")                                                 \
            for (int n = 0; n < 4; ++n)                                       \
                _Pragma("unroll")                                             \
                for (int m = 0; m < 4; ++m)                                   \
                    acc[m][n] = __builtin_amdgcn_mfma_f32_16x16x32_bf16(      \
                        af[m], bfA[n], acc[m][n], 0, 0, 0);                   \
            __builtin_amdgcn_s_setprio(0);                                    \
        }                                                                     \
        {                                                                     \
            if (DOPRE) {                                                      \
                _Pragma("unroll")                                             \
                for (int n = 0; n < 4; ++n)                                   \
                    bfA[n] = *(const bhalf8*)(Bbase                           \
                              + (size_t)(2 * (I) + 2) * 65536 + n * 256);     \
            }                                                                 \
            bhalf8 af[4];                                                     \
            _Pragma("unroll")                                                 \
            for (int m = 0; m < 4; ++m)                                       \
                af[m] = *(const bhalf8*)((const char*)smA[(S)]                \
                          + tb0 + m * 2048 + ax1);                            \
            __builtin_amdgcn_s_setprio(1);                                    \
            _Pragma("unroll")                                                 \
            for (int n = 0; n < 4; ++n)                                       \
                _Pragma("unroll")                                             \
                for (int m = 0; m < 4; ++m)                                   \
                    acc[m][n] = __builtin_amdgcn_mfma_f32_16x16x32_bf16(      \
                        af[m], bfB[n], acc[m][n], 0, 0, 0);                   \
            __builtin_amdgcn_s_setprio(0);                                    \
        }                                                                     \
    } while (0)

#define WB(N)                                                                 \
    do {                                                                      \
        asm volatile("s_waitcnt vmcnt(" #N ")" ::: "memory");                 \
        __builtin_amdgcn_s_barrier();                                         \
    } while (0)

    STEP(0, 0, 2, 1, 1);  WB(6);
    STEP(1, 1, 0, 1, 1);  WB(6);
    STEP(2, 2, 1, 1, 1);  WB(6);
    STEP(3, 0, 2, 1, 1);  WB(6);
    STEP(4, 1, 0, 1, 1);  WB(6);
    STEP(5, 2, 1, 1, 1);  WB(6);
    STEP(6, 0, 2, 1, 1);  WB(6);
    STEP(7, 1, 0, 1, 1);  WB(6);
    STEP(8, 2, 1, 1, 1);  WB(6);
    STEP(9, 0, 2, 1, 1);  WB(6);
    STEP(10, 1, 0, 1, 1); WB(6);
    STEP(11, 2, 1, 1, 1); WB(6);
    STEP(12, 0, 2, 1, 1); WB(6);
    STEP(13, 1, 0, 1, 1); WB(6);
    STEP(14, 2, 0, 0, 1); WB(4);
    STEP(15, 0, 0, 0, 0);
#undef STEP
#undef WB
#undef DMA_TILE

    float cv[4], vv[4];
#pragma unroll
    for (int n = 0; n < 4; ++n) {
        int d = dq * 256 + wn * 64 + n * 16 + lcol;
        cv[n] = cbuf[b * DD + d];
        vv[n] = vw[d];
    }

#pragma unroll
    for (int m = 0; m < 4; ++m) {
#pragma unroll
        for (int j = 0; j < 4; ++j) {
            float p = 0.f;
#pragma unroll
            for (int n = 0; n < 4; ++n)
                p += vv[n] * fast_tanhf(acc[m][n][j] + cv[n]);
            p += __shfl_xor(p, 1); p += __shfl_xor(p, 2);
            p += __shfl_xor(p, 4); p += __shfl_xor(p, 8);
            if (lcol == 0) sRed[w][m * 16 + lrow * 4 + j] = p;
        }
    }
    __syncthreads();
    if (tid < 128) {
        int r  = tid;
        int rm = r >> 6, lr = r & 63;
        float v2 = sRed[rm * 4 + 0][lr] + sRed[rm * 4 + 1][lr]
                 + sRed[rm * 4 + 2][lr] + sRed[rm * 4 + 3][lr];
        sp[((size_t)dq * BB + b) * TT + t0 + r] = v2;
    }
}

// ---------------- kernel 1-fallback: r11 scores (if ws too small) -----------
__global__ __launch_bounds__(512, 4)
void scores_fb_k(const float* __restrict__ enc, const short* __restrict__ wsWe,
                 const float* __restrict__ cbuf, const float* __restrict__ vw,
                 float* __restrict__ sp) {
    __shared__ short sA[2][4][128][8];
    __shared__ float sRed[8][64];
    const int tid  = threadIdx.x;
    const int w    = tid >> 6;
    const int wm   = w >> 2;
    const int wn   = w & 3;
    const int lane = tid & 63;
    const int lrow = lane >> 4;
    const int lcol = lane & 15;
    const int b  = blockIdx.y;
    const int tt = blockIdx.x >> 2;
    const int dq = blockIdx.x & 3;
    const int t0 = tt * 128;
    const int st  = tid >> 2;
    const int seo = tid & 3;
    const int stw = st ^ (seo << 2);
    const float* gsrc = enc + ((size_t)(b * TT + t0 + st)) * EE + seo * 8;
    fvec4 acc[4][4];
#pragma unroll
    for (int m = 0; m < 4; ++m)
#pragma unroll
        for (int n = 0; n < 4; ++n)
            acc[m][n] = (fvec4){0.f, 0.f, 0.f, 0.f};
    const char* Bbase = (const char*)wsWe + lrow * 16384
                      + (size_t)(dq * 256 + wn * 64 + lcol) * 16;
    {
        float4 x0 = *(const float4*)(gsrc);
        float4 x1 = *(const float4*)(gsrc + 4);
        *(bhalf8*)&sA[0][seo][stw][0] = cvt8(x0, x1);
    }
    __syncthreads();
#pragma unroll 2
    for (int i = 0; i < 32; ++i) {
        const int buf = i & 1;
        float4 x0, x1;
        if (i < 31) {
            x0 = *(const float4*)(gsrc + (i + 1) * 32);
            x1 = *(const float4*)(gsrc + (i + 1) * 32 + 4);
        }
        bhalf8 bf[4];
#pragma unroll
        for (int n = 0; n < 4; ++n)
            bf[n] = *(const bhalf8*)(Bbase + (size_t)i * 65536 + n * 256);
        bhalf8 af[4];
#pragma unroll
        for (int m = 0; m < 4; ++m) {
            int t = wm * 64 + m * 16 + lcol;
            af[m] = *(const bhalf8*)&sA[buf][lrow][t ^ (lrow << 2)][0];
        }
#pragma unroll
        for (int n = 0; n < 4; ++n)
#pragma unroll
            for (int m = 0; m < 4; ++m)
                acc[m][n] = __builtin_amdgcn_mfma_f32_16x16x32_bf16(af[m], bf[n], acc[m][n], 0, 0, 0);
        if (i < 31)
            *(bhalf8*)&sA[buf ^ 1][seo][stw][0] = cvt8(x0, x1);
        __syncthreads();
    }
    float cv[4], vv[4];
#pragma unroll
    for (int n = 0; n < 4; ++n) {
        int d = dq * 256 + wn * 64 + n * 16 + lcol;
        cv[n] = cbuf[b * DD + d];
        vv[n] = vw[d];
    }
#pragma unroll
    for (int m = 0; m < 4; ++m) {
#pragma unroll
        for (int j = 0; j < 4; ++j) {
            float p = 0.f;
#pragma unroll
            for (int n = 0; n < 4; ++n)
                p += vv[n] * fast_tanhf(acc[m][n][j] + cv[n]);
            p += __shfl_xor(p, 1); p += __shfl_xor(p, 2);
            p += __shfl_xor(p, 4); p += __shfl_xor(p, 8);
            if (lcol == 0) sRed[w][m * 16 + lrow * 4 + j] = p;
        }
    }
    __syncthreads();
    if (tid < 128) {
        int r  = tid;
        int rm = r >> 6, lr = r & 63;
        float v2 = sRed[rm * 4 + 0][lr] + sRed[rm * 4 + 1][lr]
                 + sRed[rm * 4 + 2][lr] + sRed[rm * 4 + 3][lr];
        sp[((size_t)dq * BB + b) * TT + t0 + r] = v2;
    }
}

// ---------------- kernel 2: sum partials + softmax over t per batch ---------
__global__ void softmax_k(const float* __restrict__ sp, float* __restrict__ alpha) {
    int b = blockIdx.x, tid = threadIdx.x;
    float s[8];
    float m = -1e30f;
#pragma unroll
    for (int i = 0; i < 8; ++i) {
        size_t idx = (size_t)b * TT + i * 256 + tid;
        s[i] = sp[idx] + sp[(size_t)BB * TT + idx]
             + sp[2 * (size_t)BB * TT + idx] + sp[3 * (size_t)BB * TT + idx];
        m = fmaxf(m, s[i]);
    }
#pragma unroll
    for (int off = 1; off < 64; off <<= 1) m = fmaxf(m, __shfl_xor(m, off));
    __shared__ float red[4], red2[4];
    if ((tid & 63) == 0) red[tid >> 6] = m;
    __syncthreads();
    m = fmaxf(fmaxf(red[0], red[1]), fmaxf(red[2], red[3]));
    float sum = 0.f;
#pragma unroll
    for (int i = 0; i < 8; ++i) { s[i] = expf(s[i] - m); sum += s[i]; }
#pragma unroll
    for (int off = 1; off < 64; off <<= 1) sum += __shfl_xor(sum, off);
    if ((tid & 63) == 0) red2[tid >> 6] = sum;
    __syncthreads();
    sum = red2[0] + red2[1] + red2[2] + red2[3];
    float inv = 1.0f / sum;
#pragma unroll
    for (int i = 0; i < 8; ++i) alpha[b * TT + i * 256 + tid] = s[i] * inv;
}

// ---------------- kernel 3: context partials from bf16 encB -----------------
// grid (16 ts, 64 b), 128 thr; slice 128 t; thread owns 8 consecutive e.
// Reads encB (256 MB total, largely L3-resident); accumulation fp32.
__global__ void ctx_k(const short* __restrict__ encB, const float* __restrict__ alpha,
                      float* __restrict__ part) {
    int ts = blockIdx.x, b = blockIdx.y, tid = threadIdx.x;
    __shared__ float sAl[128];
    sAl[tid] = alpha[b * TT + ts * 128 + tid];
    __syncthreads();
    float acc[8] = {0.f, 0.f, 0.f, 0.f, 0.f, 0.f, 0.f, 0.f};
    const short* base = encB + ((size_t)(b * TT + ts * 128)) * EE + tid * 8;
#pragma unroll 8
    for (int i = 0; i < 128; ++i) {
        bhalf8 v = *(const bhalf8*)(base + (size_t)i * EE);
        float a = sAl[i];
#pragma unroll
        for (int j = 0; j < 8; ++j)
            acc[j] += a * bf2f(v[j]);
    }
    float* dst = &part[((size_t)(ts * 64 + b)) * EE + tid * 8];
    *(float4*)dst       = (float4){acc[0], acc[1], acc[2], acc[3]};
    *(float4*)(dst + 4) = (float4){acc[4], acc[5], acc[6], acc[7]};
}

// ---------------- kernel 3-fallback: fp32 ctx (if ws too small) -------------
__global__ void ctx_fb_k(const float* __restrict__ enc, const float* __restrict__ alpha,
                         float* __restrict__ part) {
    int ts = blockIdx.x, b = blockIdx.y, tid = threadIdx.x;
    __shared__ float sAl[128];
    sAl[tid] = alpha[b * TT + ts * 128 + tid];
    __syncthreads();
    float4 a0 = {0.f, 0.f, 0.f, 0.f}, a1 = {0.f, 0.f, 0.f, 0.f};
    const float* base = enc + ((size_t)(b * TT + ts * 128)) * EE + tid * 8;
#pragma unroll 8
    for (int i = 0; i < 128; ++i) {
        float4 v0 = *(const float4*)(base + (size_t)i * EE);
        float4 v1 = *(const float4*)(base + (size_t)i * EE + 4);
        float a = sAl[i];
        a0.x += a * v0.x; a0.y += a * v0.y; a0.z += a * v0.z; a0.w += a * v0.w;
        a1.x += a * v1.x; a1.y += a * v1.y; a1.z += a * v1.z; a1.w += a * v1.w;
    }
    float* dst = &part[((size_t)(ts * 64 + b)) * EE + tid * 8];
    *(float4*)dst = a0;
    *(float4*)(dst + 4) = a1;
}

// ---------------- kernel 4: combine partials --------------------------------
__global__ void comb_k(const float* __restrict__ part, float* __restrict__ out) {
    int g = blockIdx.x * 256 + threadIdx.x;
    float s = 0.f;
#pragma unroll
    for (int ts = 0; ts < 16; ++ts) s += part[(size_t)ts * 65536 + g];
    out[g] = s;
}

extern "C" void kernel_launch(void* const* d_in, const int* in_sizes, int n_in,
                              void* d_out, int out_size, void* d_ws, size_t ws_size,
                              hipStream_t stream) {
    const float* enc  = (const float*)d_in[0];
    const float* dec  = (const float*)d_in[1];
    const float* W    = (const float*)d_in[2];
    const float* bias = (const float*)d_in[3];
    const float* vw   = (const float*)d_in[4];
    float* out = (float*)d_out;

    char* ws = (char*)d_ws;
    short* wsWe   = (short*)(ws + OFF_WE);
    float* cbuf   = (float*)(ws + OFF_C);
    float* sp     = (float*)(ws + OFF_SP);
    float* alpha  = (float*)(ws + OFF_A);
    float* part   = (float*)(ws + OFF_P);
    short* encB   = (short*)(ws + OFF_ENCB);

    prep_we_k<<<512, 256, 0, stream>>>(W, wsWe);
    prep_c_k<<<64, 256, 0, stream>>>(W, bias, dec, cbuf);
    if (ws_size >= WS_NEED) {
        prep_encb_k<<<65536, 256, 0, stream>>>(enc, encB);
        scores_k<<<dim3(64, 64), 512, 0, stream>>>(encB, wsWe, cbuf, vw, sp);
        softmax_k<<<64, 256, 0, stream>>>(sp, alpha);
        ctx_k<<<dim3(16, 64), 128, 0, stream>>>(encB, alpha, part);
    } else {
        scores_fb_k<<<dim3(64, 64), 512, 0, stream>>>(enc, wsWe, cbuf, vw, sp);
        softmax_k<<<64, 256, 0, stream>>>(sp, alpha);
        ctx_fb_k<<<dim3(16, 64), 128, 0, stream>>>(enc, alpha, part);
    }
    comb_k<<<256, 256, 0, stream>>>(part, out);
}